// Round 1
// baseline (5053.284 us; speedup 1.0000x reference)
//
#include <hip/hip_runtime.h>
#include <hip/hip_bf16.h>
#include <math.h>

// Problem constants (CrossAttention_29678224015453)
#define B_   2
#define S_   4096
#define H_   8
#define D_   160
#define QD_  1280
#define SCALE 0.07905694150420949f   // 160^-0.5

// ---------------------------------------------------------------------------
// GEMM: out[b,o,s] = sum_c W[o,c] * X[b,c,s]   (+bias for mode 2)
// mode 0: write [b][h][s][d]   (q,k layout for attention)
// mode 1: write [b][o][s]      (v layout)
// mode 2: write [b][o][s] + bias[o]  (final output)
// ---------------------------------------------------------------------------
#define BM 128
#define BN 128
#define BK 8

__global__ __launch_bounds__(256) void gemm_f32(
    const float* __restrict__ W, const float* __restrict__ X,
    float* __restrict__ out, const float* __restrict__ bias,
    int M, int N, int K, int mode)
{
  const int b  = blockIdx.z;
  const int m0 = blockIdx.y * BM;
  const int n0 = blockIdx.x * BN;
  const float* __restrict__ Xb = X + (size_t)b * K * N;

  __shared__ float At[BK][BM + 4];   // transposed A tile: At[kk][m]
  __shared__ float Bt[BK][BN + 4];

  const int t  = threadIdx.x;
  const int tx = t & 15;
  const int ty = t >> 4;

  float acc[8][8];
#pragma unroll
  for (int i = 0; i < 8; ++i)
#pragma unroll
    for (int j = 0; j < 8; ++j) acc[i][j] = 0.f;

  for (int k0 = 0; k0 < K; k0 += BK) {
    // A tile: 128 rows x 8 cols, one float4 per thread, store transposed
    {
      const int row = t >> 1;
      const int seg = (t & 1) * 4;
      const float4 w = *(const float4*)(W + (size_t)(m0 + row) * K + k0 + seg);
      At[seg + 0][row] = w.x;
      At[seg + 1][row] = w.y;
      At[seg + 2][row] = w.z;
      At[seg + 3][row] = w.w;
    }
    // B tile: 8 rows x 128 cols, one float4 per thread
    {
      const int kk = t >> 5;
      const int c4 = (t & 31) * 4;
      *(float4*)&Bt[kk][c4] = *(const float4*)(Xb + (size_t)(k0 + kk) * N + n0 + c4);
    }
    __syncthreads();
#pragma unroll
    for (int kk = 0; kk < BK; ++kk) {
      float a[8], bb[8];
      *(float4*)(a)      = *(const float4*)&At[kk][ty * 8];
      *(float4*)(a + 4)  = *(const float4*)&At[kk][ty * 8 + 4];
      *(float4*)(bb)     = *(const float4*)&Bt[kk][tx * 8];
      *(float4*)(bb + 4) = *(const float4*)&Bt[kk][tx * 8 + 4];
#pragma unroll
      for (int i = 0; i < 8; ++i)
#pragma unroll
        for (int j = 0; j < 8; ++j)
          acc[i][j] = fmaf(a[i], bb[j], acc[i][j]);
    }
    __syncthreads();
  }

#pragma unroll
  for (int i = 0; i < 8; ++i) {
    const int o = m0 + ty * 8 + i;
    if (mode == 0) {
      const int h = o / D_;
      const int d = o - h * D_;
      float* dst = out + (((size_t)b * H_ + h) * (size_t)N + n0 + tx * 8) * D_ + d;
#pragma unroll
      for (int j = 0; j < 8; ++j) dst[(size_t)j * D_] = acc[i][j];
    } else {
      float* dst = out + ((size_t)b * M + o) * (size_t)N + n0 + tx * 8;
      const float bv = (mode == 2) ? bias[o] : 0.f;
#pragma unroll
      for (int j = 0; j < 8; ++j) dst[j] = acc[i][j] + bv;
    }
  }
}

// ---------------------------------------------------------------------------
// Flash attention, fp32 accumulate, bf16 tiles in LDS (fits < 64KB).
// Q/K stored [b][h][s][d]; V stored [b][o][s] (= [b][h][d][s]).
// Output attn[b][h*160+d][s].
// Block: 256 threads, TQ=64 queries, K-loop in TK=32 chunks.
// ---------------------------------------------------------------------------
#define TQ 64
#define TK 32
#define QSTR (D_ + 2)   // 162 shorts, even => u32-pair reads stay 4B aligned
#define VSTR (TK + 2)   // 34
#define SSTR (TK + 1)   // 33

__device__ __forceinline__ unsigned short f2bf(float f) {
  unsigned u = __float_as_uint(f);
  u += 0x7fffu + ((u >> 16) & 1u);   // RNE
  return (unsigned short)(u >> 16);
}
__device__ __forceinline__ float bflo(unsigned u) { return __uint_as_float(u << 16); }
__device__ __forceinline__ float bfhi(unsigned u) { return __uint_as_float(u & 0xffff0000u); }

__global__ __launch_bounds__(256) void flash_attn(
    const float* __restrict__ qws, const float* __restrict__ kws,
    const float* __restrict__ vws, const float* __restrict__ mask,
    float* __restrict__ attn_out)
{
  const int b  = blockIdx.z;
  const int h  = blockIdx.y;
  const int q0 = blockIdx.x * TQ;
  const int t  = threadIdx.x;

  __shared__ unsigned short Qt[TQ][QSTR];
  __shared__ unsigned short Kt[TK][QSTR];
  __shared__ unsigned short Vt[D_][VSTR];
  __shared__ float Sl[TQ][SSTR];
  __shared__ float redmax[TQ][4];
  __shared__ float redsum[TQ][4];
  __shared__ float mstate[TQ], lstate[TQ], alpha_s[TQ];

  // stage Q tile (once)
  const size_t qbase = ((size_t)(b * H_ + h) * S_ + q0) * D_;
  for (int idx = t; idx < TQ * D_; idx += 256) {
    const int i = idx / D_, d = idx - i * D_;
    Qt[i][d] = f2bf(qws[qbase + (size_t)i * D_ + d]);
  }
  if (t < TQ) { mstate[t] = -1e30f; lstate[t] = 0.f; }

  float Oacc[4][10];
#pragma unroll
  for (int r = 0; r < 4; ++r)
#pragma unroll
    for (int j = 0; j < 10; ++j) Oacc[r][j] = 0.f;

  const int otx = t & 15, oty = t >> 4;   // PV/output mapping: d-block, q-block
  const int stx = t & 7,  sty = t >> 3;   // scores mapping: 2q x 4k micro
  const int rrow = t & 63, rseg = t >> 6; // reduction mapping: 1 row, 8-col seg

  for (int kp0 = 0; kp0 < S_; kp0 += TK) {
    __syncthreads();   // protect Kt/Vt/Sl from previous iteration's readers
    {
      const size_t kbase = ((size_t)(b * H_ + h) * S_ + kp0) * D_;
      for (int idx = t; idx < TK * D_; idx += 256) {
        const int i = idx / D_, d = idx - i * D_;
        Kt[i][d] = f2bf(kws[kbase + (size_t)i * D_ + d]);
      }
      const size_t vbase = ((size_t)b * QD_ + h * D_) * S_ + kp0;
      for (int idx = t; idx < D_ * TK; idx += 256) {
        const int d = idx >> 5, i = idx & 31;   // TK==32
        Vt[d][i] = f2bf(vws[vbase + (size_t)d * S_ + i]);
      }
    }
    __syncthreads();

    // ---- scores: S[2q][4k] micro-tiles, dot over d (pairs via u32 reads)
    float sacc[2][4];
#pragma unroll
    for (int r = 0; r < 2; ++r)
#pragma unroll
      for (int c = 0; c < 4; ++c) sacc[r][c] = 0.f;

    for (int d = 0; d < D_; d += 2) {
      const unsigned uq0 = *(const unsigned*)&Qt[sty * 2 + 0][d];
      const unsigned uq1 = *(const unsigned*)&Qt[sty * 2 + 1][d];
      const float q0l = bflo(uq0), q0h = bfhi(uq0);
      const float q1l = bflo(uq1), q1h = bfhi(uq1);
#pragma unroll
      for (int c = 0; c < 4; ++c) {
        const unsigned uk = *(const unsigned*)&Kt[stx * 4 + c][d];
        const float kl = bflo(uk), kh = bfhi(uk);
        sacc[0][c] = fmaf(q0l, kl, sacc[0][c]);
        sacc[0][c] = fmaf(q0h, kh, sacc[0][c]);
        sacc[1][c] = fmaf(q1l, kl, sacc[1][c]);
        sacc[1][c] = fmaf(q1h, kh, sacc[1][c]);
      }
    }
#pragma unroll
    for (int r = 0; r < 2; ++r)
#pragma unroll
      for (int c = 0; c < 4; ++c) {
        const int col = stx * 4 + c;
        Sl[sty * 2 + r][col] = sacc[r][c] * SCALE + mask[b * S_ + kp0 + col];
      }
    __syncthreads();

    // ---- online softmax: row max
    {
      float pm = -1e30f;
#pragma unroll
      for (int j = 0; j < 8; ++j) pm = fmaxf(pm, Sl[rrow][rseg * 8 + j]);
      redmax[rrow][rseg] = pm;
    }
    __syncthreads();
    if (t < TQ) {
      const float mt = fmaxf(fmaxf(redmax[t][0], redmax[t][1]),
                             fmaxf(redmax[t][2], redmax[t][3]));
      const float mo = mstate[t];
      const float mn = fmaxf(mo, mt);
      alpha_s[t] = __expf(mo - mn);
      mstate[t]  = mn;
    }
    __syncthreads();
    // ---- exp in place + partial sums
    {
      const float mn = mstate[rrow];
      float ps = 0.f;
#pragma unroll
      for (int j = 0; j < 8; ++j) {
        const int cj = rseg * 8 + j;
        const float e = __expf(Sl[rrow][cj] - mn);
        Sl[rrow][cj] = e;
        ps += e;
      }
      redsum[rrow][rseg] = ps;
    }
    __syncthreads();
    if (t < TQ)
      lstate[t] = lstate[t] * alpha_s[t] +
                  (redsum[t][0] + redsum[t][1] + redsum[t][2] + redsum[t][3]);
    __syncthreads();

    // ---- PV: O[4q][10d] += P * V, with rescale by alpha
    {
      float al[4];
#pragma unroll
      for (int r = 0; r < 4; ++r) al[r] = alpha_s[oty * 4 + r];
#pragma unroll
      for (int r = 0; r < 4; ++r)
#pragma unroll
        for (int j = 0; j < 10; ++j) Oacc[r][j] *= al[r];

      for (int kp = 0; kp < TK; ++kp) {
        float vv[10];
#pragma unroll
        for (int j = 0; j < 10; ++j)
          vv[j] = __uint_as_float(((unsigned)Vt[otx * 10 + j][kp]) << 16);
#pragma unroll
        for (int r = 0; r < 4; ++r) {
          const float p = Sl[oty * 4 + r][kp];
#pragma unroll
          for (int j = 0; j < 10; ++j)
            Oacc[r][j] = fmaf(p, vv[j], Oacc[r][j]);
        }
      }
    }
  }
  __syncthreads();

  // ---- write attn[b][h*160+d][s], normalized
#pragma unroll
  for (int r = 0; r < 4; ++r) {
    const int qrow = oty * 4 + r;
    const float inv = 1.f / lstate[qrow];
#pragma unroll
    for (int j = 0; j < 10; ++j) {
      const int d = otx * 10 + j;
      attn_out[((size_t)b * QD_ + h * D_ + d) * S_ + q0 + qrow] = Oacc[r][j] * inv;
    }
  }
}

// ---------------------------------------------------------------------------
// Launch: 4 GEMMs + flash attention.
// Workspace (fp32): q[b][h][s][d] | k[b][h][s][d] | v[b][o][s] | attn[b][o][s]
// = 4 * 41.94 MB = 167.8 MB required in d_ws.
// ---------------------------------------------------------------------------
extern "C" void kernel_launch(void* const* d_in, const int* in_sizes, int n_in,
                              void* d_out, int out_size, void* d_ws, size_t ws_size,
                              hipStream_t stream) {
  const float* x    = (const float*)d_in[0];  // hidden_states (B,1280,1,S)
  const float* c    = (const float*)d_in[1];  // context       (B,1280,1,S)
  const float* mask = (const float*)d_in[2];  // (B,S,1,1)
  const float* Wq   = (const float*)d_in[3];
  const float* Wk   = (const float*)d_in[4];
  const float* Wv   = (const float*)d_in[5];
  const float* Wout = (const float*)d_in[6];
  const float* bout = (const float*)d_in[7];
  float* out = (float*)d_out;

  const size_t NELT = (size_t)B_ * QD_ * S_;  // 10,485,760
  float* ws      = (float*)d_ws;
  float* q_ws    = ws;
  float* k_ws    = ws + NELT;
  float* v_ws    = ws + 2 * NELT;
  float* attn_ws = ws + 3 * NELT;

  const dim3 ggrid(S_ / BN, QD_ / BM, B_);   // (32, 10, 2)
  gemm_f32<<<ggrid, 256, 0, stream>>>(Wq, x, q_ws, nullptr, QD_, S_, QD_, 0);
  gemm_f32<<<ggrid, 256, 0, stream>>>(Wk, c, k_ws, nullptr, QD_, S_, QD_, 0);
  gemm_f32<<<ggrid, 256, 0, stream>>>(Wv, c, v_ws, nullptr, QD_, S_, QD_, 1);

  const dim3 agrid(S_ / TQ, H_, B_);         // (64, 8, 2)
  flash_attn<<<agrid, 256, 0, stream>>>(q_ws, k_ws, v_ws, mask, attn_ws);

  gemm_f32<<<ggrid, 256, 0, stream>>>(Wout, attn_ws, out, bout, QD_, S_, QD_, 2);
}

// Round 2
// 2345.220 us; speedup vs baseline: 2.1547x; 2.1547x over previous
//
#include <hip/hip_runtime.h>
#include <hip/hip_bf16.h>
#include <math.h>

// Problem constants (CrossAttention_29678224015453)
#define B_   2
#define S_   4096
#define H_   8
#define D_   160
#define QD_  1280
#define SCALE 0.07905694150420949f   // 160^-0.5
#define LOG2E 1.4426950408889634f

typedef unsigned short ushort_t;
typedef __attribute__((ext_vector_type(8))) short short8;
typedef __attribute__((ext_vector_type(4))) float f32x4;

#define MFMA16(a, b, c) __builtin_amdgcn_mfma_f32_16x16x32_bf16(a, b, c, 0, 0, 0)

__device__ __forceinline__ ushort_t f2bf(float f) {
  unsigned u = __float_as_uint(f);
  u += 0x7fffu + ((u >> 16) & 1u);   // RNE
  return (ushort_t)(u >> 16);
}

// ---------------------------------------------------------------------------
// GEMM: out[b,o,s] = sum_c W[o,c] * X[b,c,s]   (+bias for mode 2)
// mode 0: write bf16 [b][h][s][d]   (q,k layout for attention)
// mode 1: write bf16 [b][o][s]      (v layout)
// mode 2: write fp32 [b][o][s] + bias[o]  (final output)
// ---------------------------------------------------------------------------
#define BM 128
#define BN 128
#define BK 8

__global__ __launch_bounds__(256) void gemm_f32(
    const float* __restrict__ W, const float* __restrict__ X,
    void* __restrict__ outp, const float* __restrict__ bias,
    int M, int N, int K, int mode)
{
  const int b  = blockIdx.z;
  const int m0 = blockIdx.y * BM;
  const int n0 = blockIdx.x * BN;
  const float* __restrict__ Xb = X + (size_t)b * K * N;

  __shared__ float At[BK][BM + 4];   // transposed A tile: At[kk][m]
  __shared__ float Bt[BK][BN + 4];

  const int t  = threadIdx.x;
  const int tx = t & 15;
  const int ty = t >> 4;

  float acc[8][8];
#pragma unroll
  for (int i = 0; i < 8; ++i)
#pragma unroll
    for (int j = 0; j < 8; ++j) acc[i][j] = 0.f;

  for (int k0 = 0; k0 < K; k0 += BK) {
    {
      const int row = t >> 1;
      const int seg = (t & 1) * 4;
      const float4 w = *(const float4*)(W + (size_t)(m0 + row) * K + k0 + seg);
      At[seg + 0][row] = w.x;
      At[seg + 1][row] = w.y;
      At[seg + 2][row] = w.z;
      At[seg + 3][row] = w.w;
    }
    {
      const int kk = t >> 5;
      const int c4 = (t & 31) * 4;
      *(float4*)&Bt[kk][c4] = *(const float4*)(Xb + (size_t)(k0 + kk) * N + n0 + c4);
    }
    __syncthreads();
#pragma unroll
    for (int kk = 0; kk < BK; ++kk) {
      float a[8], bb[8];
      *(float4*)(a)      = *(const float4*)&At[kk][ty * 8];
      *(float4*)(a + 4)  = *(const float4*)&At[kk][ty * 8 + 4];
      *(float4*)(bb)     = *(const float4*)&Bt[kk][tx * 8];
      *(float4*)(bb + 4) = *(const float4*)&Bt[kk][tx * 8 + 4];
#pragma unroll
      for (int i = 0; i < 8; ++i)
#pragma unroll
        for (int j = 0; j < 8; ++j)
          acc[i][j] = fmaf(a[i], bb[j], acc[i][j]);
    }
    __syncthreads();
  }

#pragma unroll
  for (int i = 0; i < 8; ++i) {
    const int o = m0 + ty * 8 + i;
    if (mode == 0) {
      ushort_t* o16 = (ushort_t*)outp;
      const int h = o / D_;
      const int d = o - h * D_;
      ushort_t* dst = o16 + (((size_t)b * H_ + h) * (size_t)N + n0 + tx * 8) * D_ + d;
#pragma unroll
      for (int j = 0; j < 8; ++j) dst[(size_t)j * D_] = f2bf(acc[i][j]);
    } else if (mode == 1) {
      ushort_t* o16 = (ushort_t*)outp;
      ushort_t* dst = o16 + ((size_t)b * M + o) * (size_t)N + n0 + tx * 8;
#pragma unroll
      for (int j = 0; j < 8; ++j) dst[j] = f2bf(acc[i][j]);
    } else {
      float* of = (float*)outp;
      float* dst = of + ((size_t)b * M + o) * (size_t)N + n0 + tx * 8;
      const float bv = bias[o];
#pragma unroll
      for (int j = 0; j < 8; ++j) dst[j] = acc[i][j] + bv;
    }
  }
}

// ---------------------------------------------------------------------------
// MFMA flash attention (bf16 in, fp32 accumulate).
// Q/K stored bf16 [b][h][s][d]; V stored bf16 [b][o][s] (= [b][h][d][s]).
// Output attn[b][h*160+d][s] fp32.
// 256 threads = 4 waves. Each wave owns 16 q rows (wave-private softmax state,
// reductions via shfl_xor within the 16-lane quad group).
// TQ=64 queries/block, K-loop in TK=32 key chunks.
// mfma_f32_16x16x32_bf16: A[m=lane&15][k=quad*8+j], B[n=lane&15][k=quad*8+j],
// C/D: col=lane&15, row=quad*4+reg.
// ---------------------------------------------------------------------------
#define TQ 64
#define TK 32
#define QSTR 168   // 160 + 8 pad: row stride 336B = 84 dwords -> 2-way bank (free)
#define KSTR 168
#define VSTR 40    // 32 + 8 pad: 80B = 20 dwords -> 2-way
#define PSTR 40

__global__ __launch_bounds__(256) void flash_attn_mfma(
    const ushort_t* __restrict__ qws, const ushort_t* __restrict__ kws,
    const ushort_t* __restrict__ vws, const float* __restrict__ mask,
    float* __restrict__ attn_out)
{
  const int b  = blockIdx.z;
  const int h  = blockIdx.y;
  const int q0 = blockIdx.x * TQ;
  const int t  = threadIdx.x;
  const int wid  = t >> 6;
  const int lane = t & 63;
  const int l16  = lane & 15;
  const int quad = lane >> 4;

  __shared__ ushort_t Qt[TQ][QSTR];        // 21504 B
  __shared__ ushort_t Kt[TK][KSTR];        // 10752 B
  __shared__ ushort_t Vt[D_][VSTR];        // 12800 B
  __shared__ ushort_t Pw[4][16][PSTR];     //  5120 B  (wave-private P tiles)

  // ---- stage Q tile once (64 rows x 160 bf16, 16B chunks)
  const ushort_t* qg = qws + (((size_t)b * H_ + h) * S_ + q0) * D_;
  for (int idx = t; idx < TQ * 20; idx += 256) {
    const int row = idx / 20, c8 = (idx % 20) * 8;
    *(uint4*)&Qt[row][c8] = *(const uint4*)(qg + row * D_ + c8);
  }

  f32x4 Oa[10];
#pragma unroll
  for (int dt = 0; dt < 10; ++dt) Oa[dt] = {0.f, 0.f, 0.f, 0.f};
  float mrow[4] = {-1e30f, -1e30f, -1e30f, -1e30f};
  float lrow[4] = {0.f, 0.f, 0.f, 0.f};

  const int qrow_lds = wid * 16 + l16;   // this wave's A-frag row in Qt
  const float SC2 = SCALE * LOG2E;

  for (int kp0 = 0; kp0 < S_; kp0 += TK) {
    __syncthreads();   // previous iteration's Kt/Vt readers done
    {
      const ushort_t* kg = kws + (((size_t)b * H_ + h) * S_ + kp0) * D_;
      for (int idx = t; idx < TK * 20; idx += 256) {
        const int row = idx / 20, c8 = (idx % 20) * 8;
        *(uint4*)&Kt[row][c8] = *(const uint4*)(kg + row * D_ + c8);
      }
      const ushort_t* vg = vws + ((size_t)b * QD_ + h * D_) * S_ + kp0;
      for (int idx = t; idx < D_ * 4; idx += 256) {
        const int row = idx >> 2, c8 = (idx & 3) * 8;
        *(uint4*)&Vt[row][c8] = *(const uint4*)(vg + (size_t)row * S_ + c8);
      }
    }
    __syncthreads();

    // ---- QK^T: S[16q][32k] as two 16x16 C-frags, accumulate over 5 d-chunks
    f32x4 s0 = {0.f, 0.f, 0.f, 0.f};
    f32x4 s1 = {0.f, 0.f, 0.f, 0.f};
#pragma unroll
    for (int dc = 0; dc < 5; ++dc) {
      const short8 aq = *(const short8*)&Qt[qrow_lds][dc * 32 + quad * 8];
      const short8 b0 = *(const short8*)&Kt[l16][dc * 32 + quad * 8];
      const short8 b1 = *(const short8*)&Kt[16 + l16][dc * 32 + quad * 8];
      s0 = MFMA16(aq, b0, s0);
      s1 = MFMA16(aq, b1, s1);
    }

    const float mv0 = mask[b * S_ + kp0 + l16] * LOG2E;
    const float mv1 = mask[b * S_ + kp0 + 16 + l16] * LOG2E;

    // ---- online softmax (base-2 domain), wave-private per q-row
#pragma unroll
    for (int r = 0; r < 4; ++r) {
      const float t0 = s0[r] * SC2 + mv0;
      const float t1 = s1[r] * SC2 + mv1;
      float rm = fmaxf(t0, t1);
      rm = fmaxf(rm, __shfl_xor(rm, 1));
      rm = fmaxf(rm, __shfl_xor(rm, 2));
      rm = fmaxf(rm, __shfl_xor(rm, 4));
      rm = fmaxf(rm, __shfl_xor(rm, 8));
      const float mn = fmaxf(mrow[r], rm);
      const float al = exp2f(mrow[r] - mn);
      mrow[r] = mn;
      const float p0 = exp2f(t0 - mn);
      const float p1 = exp2f(t1 - mn);
      float rs = p0 + p1;
      rs += __shfl_xor(rs, 1);
      rs += __shfl_xor(rs, 2);
      rs += __shfl_xor(rs, 4);
      rs += __shfl_xor(rs, 8);
      lrow[r] = lrow[r] * al + rs;
#pragma unroll
      for (int dt = 0; dt < 10; ++dt) Oa[dt][r] *= al;
      Pw[wid][quad * 4 + r][l16]      = f2bf(p0);
      Pw[wid][quad * 4 + r][16 + l16] = f2bf(p1);
    }

    // ---- PV: O[16q][160d] += P[16q][32k] * V[32k][160d]
    // (Pw write->read is wave-private; HW LDS ops are in-order per wave)
    const short8 ap = *(const short8*)&Pw[wid][l16][quad * 8];
#pragma unroll
    for (int dt = 0; dt < 10; ++dt) {
      const short8 bv = *(const short8*)&Vt[dt * 16 + l16][quad * 8];
      Oa[dt] = MFMA16(ap, bv, Oa[dt]);
    }
  }

  // ---- normalize and write attn[b][h*160+d][s]
#pragma unroll
  for (int r = 0; r < 4; ++r) {
    const float inv = 1.f / lrow[r];
    const int qq = q0 + wid * 16 + quad * 4 + r;
#pragma unroll
    for (int dt = 0; dt < 10; ++dt) {
      const int d = dt * 16 + l16;
      attn_out[((size_t)b * QD_ + h * D_ + d) * S_ + qq] = Oa[dt][r] * inv;
    }
  }
}

// ---------------------------------------------------------------------------
// Workspace layout (ws_size >= ~105 MB):
//   q_ws bf16 [b][h][s][d]  : NELT ushort
//   k_ws bf16 [b][h][s][d]  : NELT ushort
//   v_ws bf16 [b][o][s]     : NELT ushort
//   attn_ws fp32 [b][o][s]  : NELT float
// ---------------------------------------------------------------------------
extern "C" void kernel_launch(void* const* d_in, const int* in_sizes, int n_in,
                              void* d_out, int out_size, void* d_ws, size_t ws_size,
                              hipStream_t stream) {
  const float* x    = (const float*)d_in[0];  // hidden_states (B,1280,1,S)
  const float* c    = (const float*)d_in[1];  // context       (B,1280,1,S)
  const float* mask = (const float*)d_in[2];  // (B,S,1,1)
  const float* Wq   = (const float*)d_in[3];
  const float* Wk   = (const float*)d_in[4];
  const float* Wv   = (const float*)d_in[5];
  const float* Wout = (const float*)d_in[6];
  const float* bout = (const float*)d_in[7];
  float* out = (float*)d_out;

  const size_t NELT = (size_t)B_ * QD_ * S_;  // 10,485,760
  ushort_t* q_ws = (ushort_t*)d_ws;
  ushort_t* k_ws = q_ws + NELT;
  ushort_t* v_ws = k_ws + NELT;
  float* attn_ws = (float*)(v_ws + NELT);

  const dim3 ggrid(S_ / BN, QD_ / BM, B_);   // (32, 10, 2)
  gemm_f32<<<ggrid, 256, 0, stream>>>(Wq, x, q_ws, nullptr, QD_, S_, QD_, 0);
  gemm_f32<<<ggrid, 256, 0, stream>>>(Wk, c, k_ws, nullptr, QD_, S_, QD_, 0);
  gemm_f32<<<ggrid, 256, 0, stream>>>(Wv, c, v_ws, nullptr, QD_, S_, QD_, 1);

  const dim3 agrid(S_ / TQ, H_, B_);         // (64, 8, 2)
  flash_attn_mfma<<<agrid, 256, 0, stream>>>(q_ws, k_ws, v_ws, mask, attn_ws);

  gemm_f32<<<ggrid, 256, 0, stream>>>(Wout, attn_ws, out, bout, QD_, S_, QD_, 2);
}

// Round 4
// 798.411 us; speedup vs baseline: 6.3292x; 2.9374x over previous
//
#include <hip/hip_runtime.h>
#include <hip/hip_bf16.h>
#include <math.h>

// Problem constants (CrossAttention_29678224015453)
#define B_   2
#define S_   4096
#define H_   8
#define D_   160
#define QD_  1280
#define SCALE 0.07905694150420949f   // 160^-0.5
#define LOG2E 1.4426950408889634f

typedef unsigned short ushort_t;
typedef __attribute__((ext_vector_type(8))) short short8;
typedef __attribute__((ext_vector_type(4))) float f32x4;

#define MFMA16(a, b, c) __builtin_amdgcn_mfma_f32_16x16x32_bf16(a, b, c, 0, 0, 0)

__device__ __forceinline__ ushort_t f2bf(float f) {
  unsigned u = __float_as_uint(f);
  u += 0x7fffu + ((u >> 16) & 1u);   // RNE
  return (ushort_t)(u >> 16);
}

// async 16B global->LDS (lds dest = wave-uniform base + lane*16)
__device__ __forceinline__ void gload_lds16(const ushort_t* g, ushort_t* l) {
  __builtin_amdgcn_global_load_lds(
      (const __attribute__((address_space(1))) unsigned int*)(g),
      (__attribute__((address_space(3))) unsigned int*)(l), 16, 0, 0);
}

// DPP helpers: reduce over the 16-lane row group (l16 dimension)
template <int CTRL>
__device__ __forceinline__ float dpp_mov(float x) {
  return __int_as_float(
      __builtin_amdgcn_update_dpp(0, __float_as_int(x), CTRL, 0xF, 0xF, true));
}
__device__ __forceinline__ float row_max16(float x) {
  x = fmaxf(x, dpp_mov<0xB1>(x));   // quad_perm(1,0,3,2)  xor 1
  x = fmaxf(x, dpp_mov<0x4E>(x));   // quad_perm(2,3,0,1)  xor 2
  x = fmaxf(x, dpp_mov<0x124>(x));  // row_ror:4
  x = fmaxf(x, dpp_mov<0x128>(x));  // row_ror:8
  return x;
}
__device__ __forceinline__ float row_sum16(float x) {
  x += dpp_mov<0xB1>(x);
  x += dpp_mov<0x4E>(x);
  x += dpp_mov<0x124>(x);
  x += dpp_mov<0x128>(x);
  return x;
}

// ---------------------------------------------------------------------------
// Transpose+convert: src fp32 [b][C=1280][S=4096] -> dst bf16 [b][S][C]
// ---------------------------------------------------------------------------
__global__ __launch_bounds__(256) void transpose_cvt(
    const float* __restrict__ src, ushort_t* __restrict__ dst)
{
  const int b = blockIdx.z;
  const int s0 = blockIdx.x * 32;
  const int c0 = blockIdx.y * 32;
  __shared__ float T[32][33];
  const int t = threadIdx.x;
  const int sl = t & 31, cr = t >> 5;
#pragma unroll
  for (int i = 0; i < 4; ++i)
    T[cr + i * 8][sl] = src[((size_t)b * QD_ + c0 + cr + i * 8) * S_ + s0 + sl];
  __syncthreads();
  const int cl = (t & 7) * 4, sr = t >> 3;
  ushort4 v;
  v.x = f2bf(T[cl + 0][sr]);
  v.y = f2bf(T[cl + 1][sr]);
  v.z = f2bf(T[cl + 2][sr]);
  v.w = f2bf(T[cl + 3][sr]);
  *(ushort4*)(dst + ((size_t)b * S_ + s0 + sr) * QD_ + c0 + cl) = v;
}

// ---------------------------------------------------------------------------
// Weight convert fp32 -> bf16 (4 matrices, blockIdx.y selects)
// ---------------------------------------------------------------------------
__global__ __launch_bounds__(256) void cvt_w(
    const float* __restrict__ w0, const float* __restrict__ w1,
    const float* __restrict__ w2, const float* __restrict__ w3,
    ushort_t* __restrict__ o0, ushort_t* __restrict__ o1,
    ushort_t* __restrict__ o2, ushort_t* __restrict__ o3)
{
  const int which = blockIdx.y;
  const float* s = which == 0 ? w0 : which == 1 ? w1 : which == 2 ? w2 : w3;
  ushort_t* d    = which == 0 ? o0 : which == 1 ? o1 : which == 2 ? o2 : o3;
  const size_t i = ((size_t)blockIdx.x * 256 + threadIdx.x) * 4;
  const float4 f = *(const float4*)(s + i);
  ushort4 v;
  v.x = f2bf(f.x); v.y = f2bf(f.y); v.z = f2bf(f.z); v.w = f2bf(f.w);
  *(ushort4*)(d + i) = v;
}

// ---------------------------------------------------------------------------
// bf16 MFMA GEMM: C[m][n] = sum_k A[m][k] * B[n][k]  (both k-contiguous)
// 128x128 tile, BK=32, 256 thr = 4 waves in 2x2, each wave 64x64 (4x4 frags).
// LDS granule-XOR swizzle: data granule g of row r stored at slot g^(r&3)
// -> global_load_lds stays contiguous AND frag ds_read_b128 is 2-way (free).
// mode 0: C bf16 [M][N].  mode 1: C fp32 [M][N] + bias[m].
// ---------------------------------------------------------------------------
#define GBM 128
#define GBN 128
#define GBK 32

__global__ __launch_bounds__(256) void gemm_mfma(
    const ushort_t* __restrict__ A, const ushort_t* __restrict__ B,
    void* __restrict__ Cp, const float* __restrict__ bias,
    int M, int N, int K, int mode,
    size_t strideA, size_t strideB, size_t strideC)
{
  const int bz = blockIdx.z;
  const int m0 = blockIdx.y * GBM;
  const int n0 = blockIdx.x * GBN;
  const ushort_t* __restrict__ Ab = A + (size_t)bz * strideA;
  const ushort_t* __restrict__ Bb = B + (size_t)bz * strideB;

  __shared__ ushort_t As[GBM * GBK];   // 8 KB
  __shared__ ushort_t Bs[GBN * GBK];   // 8 KB

  const int t = threadIdx.x;
  const int wid = t >> 6, lane = t & 63;
  const int l16 = lane & 15, quad = lane >> 4;
  const int wm = (wid >> 1) * 64, wn = (wid & 1) * 64;

  f32x4 acc[4][4];
#pragma unroll
  for (int i = 0; i < 4; ++i)
#pragma unroll
    for (int j = 0; j < 4; ++j) acc[i][j] = {0.f, 0.f, 0.f, 0.f};

  for (int k0 = 0; k0 < K; k0 += GBK) {
    __syncthreads();   // previous iteration's frag readers done
#pragma unroll
    for (int i = 0; i < 2; ++i) {
      const int G = (i * 4 + wid) * 64 + lane;   // granule id in tile
      const int r = G >> 2, sl = G & 3;
      const int g = sl ^ (r & 3);                 // XOR-swizzled source granule
      gload_lds16(Ab + (size_t)(m0 + r) * K + k0 + g * 8, &As[(i * 4 + wid) * 512]);
      gload_lds16(Bb + (size_t)(n0 + r) * K + k0 + g * 8, &Bs[(i * 4 + wid) * 512]);
    }
    __syncthreads();   // drains vmcnt(0) -> LDS tiles valid

    short8 af[4], bfr[4];
#pragma unroll
    for (int mt = 0; mt < 4; ++mt) {
      const int r = wm + mt * 16 + l16;
      af[mt] = *(const short8*)&As[r * 32 + ((quad ^ (r & 3)) << 3)];
    }
#pragma unroll
    for (int nt = 0; nt < 4; ++nt) {
      const int r = wn + nt * 16 + l16;
      bfr[nt] = *(const short8*)&Bs[r * 32 + ((quad ^ (r & 3)) << 3)];
    }
#pragma unroll
    for (int mt = 0; mt < 4; ++mt)
#pragma unroll
      for (int nt = 0; nt < 4; ++nt)
        acc[mt][nt] = MFMA16(af[mt], bfr[nt], acc[mt][nt]);
  }

  // epilogue: C/D layout col=lane&15 (n), row=quad*4+reg (m)
  if (mode == 0) {
    ushort_t* C = (ushort_t*)Cp + (size_t)bz * strideC;
#pragma unroll
    for (int mt = 0; mt < 4; ++mt)
#pragma unroll
      for (int r = 0; r < 4; ++r) {
        const int row = m0 + wm + mt * 16 + quad * 4 + r;
        ushort_t* cr = C + (size_t)row * N + n0 + wn + l16;
#pragma unroll
        for (int nt = 0; nt < 4; ++nt) cr[nt * 16] = f2bf(acc[mt][nt][r]);
      }
  } else {
    float* C = (float*)Cp + (size_t)bz * strideC;
#pragma unroll
    for (int mt = 0; mt < 4; ++mt)
#pragma unroll
      for (int r = 0; r < 4; ++r) {
        const int row = m0 + wm + mt * 16 + quad * 4 + r;
        const float bv = bias[row];
        float* cr = C + (size_t)row * N + n0 + wn + l16;
#pragma unroll
        for (int nt = 0; nt < 4; ++nt) cr[nt * 16] = acc[mt][nt][r] + bv;
      }
  }
}

// ---------------------------------------------------------------------------
// MFMA flash attention. Q/K bf16 [b][s][1280] (head h at col h*160);
// V bf16 [b][o][s]. Output bf16 [b][s][1280].
// 4 waves; each wave owns 16 q-rows, Q frags in registers (no Qt LDS).
// TK=64 keys per chunk. DPP softmax reductions (no DS). Rescale skipped
// when no row max changed.
// ---------------------------------------------------------------------------
#define TQ 64
#define TK 64
#define KSTR 164   // 82 dwords = 18 mod 32 -> ideal bank spread for frag reads
#define VSTR 68    // 34 dwords = 2 mod 32  -> ideal
#define PSTR 68

__global__ __launch_bounds__(256) void flash_attn_mfma(
    const ushort_t* __restrict__ qws, const ushort_t* __restrict__ kws,
    const ushort_t* __restrict__ vws, const float* __restrict__ mask,
    ushort_t* __restrict__ attn_out)
{
  const int b  = blockIdx.z;
  const int h  = blockIdx.y;
  const int q0 = blockIdx.x * TQ;
  const int t  = threadIdx.x;
  const int wid  = t >> 6;
  const int lane = t & 63;
  const int l16  = lane & 15;
  const int quad = lane >> 4;

  __shared__ ushort_t Kt[TK][KSTR];       // 20992 B
  __shared__ ushort_t Vt[D_][VSTR];       // 21760 B
  __shared__ ushort_t Pw[4][16][PSTR];    //  8704 B  (wave-private)

  // ---- Q fragments in registers: A[m=l16][k=dc*32 + quad*8 + j]
  short8 aq[5];
  {
    const ushort_t* qrow =
        qws + ((size_t)(b * S_ + q0 + wid * 16 + l16)) * QD_ + h * D_;
#pragma unroll
    for (int dc = 0; dc < 5; ++dc)
      aq[dc] = *(const short8*)(qrow + dc * 32 + quad * 8);   // FIX: + quad*8
  }

  f32x4 Oa[10];
#pragma unroll
  for (int dt = 0; dt < 10; ++dt) Oa[dt] = {0.f, 0.f, 0.f, 0.f};
  float mrow[4] = {-1e30f, -1e30f, -1e30f, -1e30f};
  float lrow[4] = {0.f, 0.f, 0.f, 0.f};
  const float SC2 = SCALE * LOG2E;

  for (int kp0 = 0; kp0 < S_; kp0 += TK) {
    __syncthreads();
    {
      const ushort_t* kg = kws + ((size_t)(b * S_ + kp0)) * QD_ + h * D_;
#pragma unroll
      for (int i = 0; i < 5; ++i) {      // 64 rows x 20 granules
        const int idx = i * 256 + t;
        const int row = idx / 20, g = idx - row * 20;
        *(uint4*)&Kt[row][g * 8] = *(const uint4*)(kg + (size_t)row * QD_ + g * 8);
      }
      const ushort_t* vg = vws + ((size_t)b * QD_ + h * D_) * S_ + kp0;
#pragma unroll
      for (int i = 0; i < 5; ++i) {      // 160 rows x 8 granules
        const int idx = i * 256 + t;
        const int row = idx >> 3, g = idx & 7;
        *(uint4*)&Vt[row][g * 8] = *(const uint4*)(vg + (size_t)row * S_ + g * 8);
      }
    }
    __syncthreads();

    // ---- QK^T: S[16q][64k] as four 16x16 C-frags over 5 d-chunks
    f32x4 s[4];
#pragma unroll
    for (int c = 0; c < 4; ++c) s[c] = {0.f, 0.f, 0.f, 0.f};
#pragma unroll
    for (int dc = 0; dc < 5; ++dc) {
      const short8 a = aq[dc];
#pragma unroll
      for (int c = 0; c < 4; ++c) {
        const short8 bb = *(const short8*)&Kt[c * 16 + l16][dc * 32 + quad * 8];
        s[c] = MFMA16(a, bb, s[c]);
      }
    }

    float mv[4];
#pragma unroll
    for (int c = 0; c < 4; ++c)
      mv[c] = mask[b * S_ + kp0 + c * 16 + l16] * LOG2E;

    // ---- online softmax (base-2), DPP reductions over the 16 k-lanes
    float al[4];
    bool need = false;
#pragma unroll
    for (int r = 0; r < 4; ++r) {
      const float t0 = s[0][r] * SC2 + mv[0];
      const float t1 = s[1][r] * SC2 + mv[1];
      const float t2 = s[2][r] * SC2 + mv[2];
      const float t3 = s[3][r] * SC2 + mv[3];
      float rm = fmaxf(fmaxf(t0, t1), fmaxf(t2, t3));
      rm = row_max16(rm);
      const float mn = fmaxf(mrow[r], rm);
      al[r] = exp2f(mrow[r] - mn);
      mrow[r] = mn;
      const float p0 = exp2f(t0 - mn);
      const float p1 = exp2f(t1 - mn);
      const float p2 = exp2f(t2 - mn);
      const float p3 = exp2f(t3 - mn);
      float rs = (p0 + p1) + (p2 + p3);
      rs = row_sum16(rs);
      lrow[r] = lrow[r] * al[r] + rs;
      Pw[wid][quad * 4 + r][l16]      = f2bf(p0);
      Pw[wid][quad * 4 + r][16 + l16] = f2bf(p1);
      Pw[wid][quad * 4 + r][32 + l16] = f2bf(p2);
      Pw[wid][quad * 4 + r][48 + l16] = f2bf(p3);
      need |= (al[r] != 1.f);
    }
    if (__any(need)) {
      const f32x4 alv = {al[0], al[1], al[2], al[3]};
#pragma unroll
      for (int dt = 0; dt < 10; ++dt) Oa[dt] *= alv;
    }

    // ---- PV: O[16q][160d] += P[16q][64k] * V[64k][160d] (2 k-steps)
    const short8 ap0 = *(const short8*)&Pw[wid][l16][quad * 8];
    const short8 ap1 = *(const short8*)&Pw[wid][l16][32 + quad * 8];
#pragma unroll
    for (int dt = 0; dt < 10; ++dt) {
      const short8 bv0 = *(const short8*)&Vt[dt * 16 + l16][quad * 8];
      const short8 bv1 = *(const short8*)&Vt[dt * 16 + l16][32 + quad * 8];
      Oa[dt] = MFMA16(ap0, bv0, Oa[dt]);
      Oa[dt] = MFMA16(ap1, bv1, Oa[dt]);
    }
  }

  // ---- normalize, write bf16 attn[b][s][h*160+d]
#pragma unroll
  for (int r = 0; r < 4; ++r) {
    const float inv = 1.f / lrow[r];
    const int qq = q0 + wid * 16 + quad * 4 + r;
    ushort_t* orow = attn_out + ((size_t)(b * S_ + qq)) * QD_ + h * D_;
#pragma unroll
    for (int dt = 0; dt < 10; ++dt)
      orow[dt * 16 + l16] = f2bf(Oa[dt][r] * inv);
  }
}

// ---------------------------------------------------------------------------
// Workspace (bytes): Xt 21.0M | Ct 21.0M | Wq/Wk/Wv/Wout bf16 4x3.28M |
// q_ws 21.0M | k_ws 21.0M | v_ws 21.0M | attn_ws 21.0M  -> ~160 MB total
// ---------------------------------------------------------------------------
extern "C" void kernel_launch(void* const* d_in, const int* in_sizes, int n_in,
                              void* d_out, int out_size, void* d_ws, size_t ws_size,
                              hipStream_t stream) {
  const float* x    = (const float*)d_in[0];
  const float* c    = (const float*)d_in[1];
  const float* mask = (const float*)d_in[2];
  const float* Wq   = (const float*)d_in[3];
  const float* Wk   = (const float*)d_in[4];
  const float* Wv   = (const float*)d_in[5];
  const float* Wout = (const float*)d_in[6];
  const float* bout = (const float*)d_in[7];
  float* out = (float*)d_out;

  const size_t PB   = (size_t)S_ * QD_;     // 5,242,880 per batch
  const size_t NELT = (size_t)B_ * PB;      // 10,485,760
  const size_t WN   = (size_t)QD_ * QD_;    // 1,638,400

  ushort_t* Xt    = (ushort_t*)d_ws;
  ushort_t* Ct    = Xt + NELT;
  ushort_t* Wqb   = Ct + NELT;
  ushort_t* Wkb   = Wqb + WN;
  ushort_t* Wvb   = Wkb + WN;
  ushort_t* Woutb = Wvb + WN;
  ushort_t* q_ws  = Woutb + WN;
  ushort_t* k_ws  = q_ws + NELT;
  ushort_t* v_ws  = k_ws + NELT;
  ushort_t* attn_ws = v_ws + NELT;

  const dim3 tgrid(S_ / 32, QD_ / 32, B_);          // (128, 40, 2)
  transpose_cvt<<<tgrid, 256, 0, stream>>>(x, Xt);
  transpose_cvt<<<tgrid, 256, 0, stream>>>(c, Ct);
  cvt_w<<<dim3(WN / 1024, 4, 1), 256, 0, stream>>>(Wq, Wk, Wv, Wout,
                                                   Wqb, Wkb, Wvb, Woutb);

  // q = Xt(4096x1280) * Wq^T -> q_ws [b][s][o] bf16
  const dim3 gq(QD_ / GBN, S_ / GBM, B_);           // (10, 32, 2)
  gemm_mfma<<<gq, 256, 0, stream>>>(Xt, Wqb, q_ws, nullptr,
                                    S_, QD_, QD_, 0, PB, 0, PB);
  gemm_mfma<<<gq, 256, 0, stream>>>(Ct, Wkb, k_ws, nullptr,
                                    S_, QD_, QD_, 0, PB, 0, PB);
  // v = Wv(1280x1280) * Ct^T -> v_ws [b][o][s] bf16
  const dim3 gv(S_ / GBN, QD_ / GBM, B_);           // (32, 10, 2)
  gemm_mfma<<<gv, 256, 0, stream>>>(Wvb, Ct, v_ws, nullptr,
                                    QD_, S_, QD_, 0, 0, PB, PB);

  const dim3 agrid(S_ / TQ, H_, B_);                // (64, 8, 2)
  flash_attn_mfma<<<agrid, 256, 0, stream>>>(q_ws, k_ws, v_ws, mask, attn_ws);

  // out = Wout(1280x1280) * attn^T + bout -> fp32 [b][o][s]
  gemm_mfma<<<gv, 256, 0, stream>>>(Woutb, attn_ws, out, bout,
                                    QD_, S_, QD_, 1, 0, PB, PB);
}